// Round 4
// baseline (2935.468 us; speedup 1.0000x reference)
//
#include <hip/hip_runtime.h>

#define NUM_USERS_ 50000
#define NUM_ITEMS_ 100000
#define NN 150000            // NUM_USERS + NUM_ITEMS
#define DD 128
#define NNZ_ 4800000
#define NLAYERS_ 3

// ---------------- CSR build (deterministic, edge-order stable) ----------------

__global__ void hist_kernel(const int* __restrict__ rows, int* __restrict__ counts, int nnz) {
    int e = blockIdx.x * blockDim.x + threadIdx.x;
    if (e < nnz) atomicAdd(&counts[rows[e]], 1);
}

__global__ __launch_bounds__(1024) void scan_kernel(const int* __restrict__ counts,
                                                    int* __restrict__ row_ptr,
                                                    int* __restrict__ cursor, int n) {
    __shared__ int partials[1024];
    int tid = threadIdx.x;
    int chunk = (n + 1023) >> 10;
    int start = tid * chunk;
    int end = start + chunk;
    if (end > n) end = n;
    if (start > n) start = n;
    int sum = 0;
    for (int i = start; i < end; ++i) sum += counts[i];
    partials[tid] = sum;
    __syncthreads();
    for (int off = 1; off < 1024; off <<= 1) {
        int v = (tid >= off) ? partials[tid - off] : 0;
        __syncthreads();
        partials[tid] += v;
        __syncthreads();
    }
    int run = (tid == 0) ? 0 : partials[tid - 1];
    for (int i = start; i < end; ++i) {
        int c = counts[i];
        row_ptr[i] = run;
        cursor[i]  = run;
        run += c;
    }
    if (tid == 1023) row_ptr[n] = partials[1023];
}

// scatter edge indices (arbitrary within-row order; fixed by sort below)
__global__ void scatter_kernel(const int* __restrict__ rows, int* __restrict__ cursor,
                               int* __restrict__ eidx, int nnz) {
    int e = blockIdx.x * blockDim.x + threadIdx.x;
    if (e < nnz) {
        int pos = atomicAdd(&cursor[rows[e]], 1);
        eidx[pos] = e;
    }
}

// per-row insertion sort of eidx ascending -> stable edge order (matches np.add.at)
__global__ void sortrows_kernel(const int* __restrict__ row_ptr, int* __restrict__ eidx) {
    int row = blockIdx.x * blockDim.x + threadIdx.x;
    if (row >= NN) return;
    int beg = row_ptr[row], end = row_ptr[row + 1];
    for (int i = beg + 1; i < end; ++i) {
        int key = eidx[i];
        int j = i - 1;
        while (j >= beg && eidx[j] > key) { eidx[j + 1] = eidx[j]; --j; }
        eidx[j + 1] = key;
    }
}

__global__ void materialize_kernel(const int* __restrict__ eidx, const int* __restrict__ cols,
                                   const float* __restrict__ vals,
                                   int* __restrict__ ccol, float* __restrict__ cval, int nnz) {
    int j = blockIdx.x * blockDim.x + threadIdx.x;
    if (j < nnz) {
        int e = eidx[j];
        ccol[j] = cols[e];
        cval[j] = vals[e];
    }
}

// ego0 = concat(user_emb, item_emb)
__global__ void concat_kernel(const float4* __restrict__ u, const float4* __restrict__ it,
                              float4* __restrict__ ego) {
    long long i = (long long)blockIdx.x * blockDim.x + threadIdx.x;
    const long long nu  = (long long)NUM_USERS_ * (DD / 4);
    const long long tot = (long long)NN * (DD / 4);
    if (i < nu) ego[i] = u[i];
    else if (i < tot) ego[i] = it[i - nu];
}

// ---------------- row norms of noise: numpy AVX512 npyv pairwise order ----------------
// FLOAT_pairwise_sum SIMD path, W=16 lanes, 4 vector accumulators, n=128:
//   r0_l = q[l]+q[64+l]; r1_l = q[16+l]+q[80+l]; r2_l = q[32+l]+q[96+l]; r3_l = q[48+l]+q[112+l]
//   rs_l = (r0_l+r1_l) + (r2_l+r3_l)
// npyv_sum_f32 halving tree: b_l = rs_l+rs_{l+8}; c_l = b_l+b_{l+4};
//   res = (c0+c2) + (c1+c3)
__global__ void norm_kernel(const float* __restrict__ noise, float* __restrict__ nrm, int total) {
    int i = blockIdx.x * blockDim.x + threadIdx.x;
    if (i >= total) return;
    const float* x = noise + (long long)i * DD;
    float q[DD];
    #pragma unroll
    for (int j = 0; j < DD; ++j) q[j] = __fmul_rn(x[j], x[j]);
    float rs[16];
    #pragma unroll
    for (int l = 0; l < 16; ++l) {
        float r0 = __fadd_rn(q[l],      q[64 + l]);
        float r1 = __fadd_rn(q[16 + l], q[80 + l]);
        float r2 = __fadd_rn(q[32 + l], q[96 + l]);
        float r3 = __fadd_rn(q[48 + l], q[112 + l]);
        rs[l] = __fadd_rn(__fadd_rn(r0, r1), __fadd_rn(r2, r3));
    }
    float b[8];
    #pragma unroll
    for (int l = 0; l < 8; ++l) b[l] = __fadd_rn(rs[l], rs[l + 8]);
    float c[4];
    #pragma unroll
    for (int l = 0; l < 4; ++l) c[l] = __fadd_rn(b[l], b[l + 4]);
    float d0 = __fadd_rn(c[0], c[2]);
    float d1 = __fadd_rn(c[1], c[3]);
    float s  = __fadd_rn(d0, d1);
    nrm[i] = __fsqrt_rn(s);
}

// ---------------- fused SpMM + noise + accumulate (strict f32, np op order) ----------------
// one wave per row; lane owns columns [2*lane, 2*lane+1]
template <int LAYER>   // 1, 2, 3
__global__ __launch_bounds__(256) void layer_kernel(
    const int* __restrict__ row_ptr, const int* __restrict__ ccol,
    const float* __restrict__ cval, const float* __restrict__ x,
    const float* __restrict__ noise_k, const float* __restrict__ nrm_k,
    float* __restrict__ y_out, float* __restrict__ acc) {
    int wave = threadIdx.x >> 6;
    int lane = threadIdx.x & 63;
    int row  = blockIdx.x * 4 + wave;
    if (row >= NN) return;

    int beg = row_ptr[row];
    int end = row_ptr[row + 1];

    float a0 = 0.0f, a1 = 0.0f;
    for (int j = beg; j < end; ++j) {
        int   c = ccol[j];
        float v = cval[j];
        float2 xv = ((const float2*)(x + (long long)c * DD))[lane];
        a0 = __fadd_rn(a0, __fmul_rn(v, xv.x));   // round product, then add: matches np
        a1 = __fadd_rn(a1, __fmul_rn(v, xv.y));
    }

    float2 nv = ((const float2*)(noise_k + (long long)row * DD))[lane];
    float nrm = nrm_k[row];

    float s0 = (a0 > 0.0f) ? 1.0f : ((a0 < 0.0f) ? -1.0f : 0.0f);
    float s1 = (a1 > 0.0f) ? 1.0f : ((a1 < 0.0f) ? -1.0f : 0.0f);
    // np order: nk = n / nrm;  t = (sign * nk) * 0.2f;  ego = a + t
    float q0 = __fdiv_rn(nv.x, nrm);
    float q1 = __fdiv_rn(nv.y, nrm);
    float t0 = __fmul_rn(__fmul_rn(s0, q0), 0.2f);
    float t1 = __fmul_rn(__fmul_rn(s1, q1), 0.2f);
    float e0 = __fadd_rn(a0, t0);
    float e1 = __fadd_rn(a1, t1);

    if (LAYER < 3) {
        ((float2*)(y_out + (long long)row * DD))[lane] = make_float2(e0, e1);
    }

    float2* ac = (float2*)(acc + (long long)row * DD);
    if (LAYER == 1) {
        ac[lane] = make_float2(e0, e1);
    } else if (LAYER == 2) {
        float2 p = ac[lane];
        ac[lane] = make_float2(__fadd_rn(p.x, e0), __fadd_rn(p.y, e1));
    } else {
        float2 p = ac[lane];
        ac[lane] = make_float2(__fdiv_rn(__fadd_rn(p.x, e0), 3.0f),
                               __fdiv_rn(__fadd_rn(p.y, e1), 3.0f));
    }
}

extern "C" void kernel_launch(void* const* d_in, const int* in_sizes, int n_in,
                              void* d_out, int out_size, void* d_ws, size_t ws_size,
                              hipStream_t stream) {
    const float* user  = (const float*)d_in[0];
    const float* item  = (const float*)d_in[1];
    const float* vals  = (const float*)d_in[2];
    const float* noise = (const float*)d_in[3];
    const int*   rows  = (const int*)d_in[4];
    const int*   cols  = (const int*)d_in[5];
    float* out = (float*)d_out;   // doubles as the acc buffer

    char* ws = (char*)d_ws;
    size_t off = 0;
    auto alloc = [&](size_t bytes) -> char* {
        char* p = ws + off;
        off = (off + bytes + 255) & ~(size_t)255;
        return p;
    };

    int*   counts  = (int*)  alloc((size_t)NN * 4);
    int*   row_ptr = (int*)  alloc((size_t)(NN + 1) * 4);
    int*   cursor  = (int*)  alloc((size_t)NN * 4);
    int*   eidx    = (int*)  alloc((size_t)NNZ_ * 4);
    int*   ccol    = (int*)  alloc((size_t)NNZ_ * 4);
    float* cval    = (float*)alloc((size_t)NNZ_ * 4);
    float* nrm     = (float*)alloc((size_t)NLAYERS_ * NN * 4);
    float* ego_a   = (float*)alloc((size_t)NN * DD * 4);
    float* ego_b   = (float*)alloc((size_t)NN * DD * 4);

    hipMemsetAsync(counts, 0, (size_t)NN * 4, stream);

    const int TB = 256;
    hist_kernel<<<(NNZ_ + TB - 1) / TB, TB, 0, stream>>>(rows, counts, NNZ_);
    scan_kernel<<<1, 1024, 0, stream>>>(counts, row_ptr, cursor, NN);
    scatter_kernel<<<(NNZ_ + TB - 1) / TB, TB, 0, stream>>>(rows, cursor, eidx, NNZ_);
    sortrows_kernel<<<(NN + TB - 1) / TB, TB, 0, stream>>>(row_ptr, eidx);
    materialize_kernel<<<(NNZ_ + TB - 1) / TB, TB, 0, stream>>>(eidx, cols, vals, ccol, cval, NNZ_);

    concat_kernel<<<((NN * (DD / 4)) + TB - 1) / TB, TB, 0, stream>>>(
        (const float4*)user, (const float4*)item, (float4*)ego_a);

    norm_kernel<<<((NLAYERS_ * NN) + TB - 1) / TB, TB, 0, stream>>>(noise, nrm, NLAYERS_ * NN);

    const long long slab = (long long)NN * DD;
    int lgrid = (NN + 3) / 4;
    layer_kernel<1><<<lgrid, TB, 0, stream>>>(row_ptr, ccol, cval, ego_a, noise + 0 * slab, nrm + 0 * NN, ego_b, out);
    layer_kernel<2><<<lgrid, TB, 0, stream>>>(row_ptr, ccol, cval, ego_b, noise + 1 * slab, nrm + 1 * NN, ego_a, out);
    layer_kernel<3><<<lgrid, TB, 0, stream>>>(row_ptr, ccol, cval, ego_a, noise + 2 * slab, nrm + 2 * NN, ego_b, out);
}

// Round 5
// 2277.448 us; speedup vs baseline: 1.2889x; 1.2889x over previous
//
#include <hip/hip_runtime.h>

#define NUM_USERS_ 50000
#define NUM_ITEMS_ 100000
#define NN 150000            // NUM_USERS + NUM_ITEMS
#define DD 128
#define NNZ_ 4800000
#define NLAYERS_ 3
#define SLOT 73              // per-row LDS sort budget (73 % 32 = 9 -> conflict-spread)

// ---------------- CSR build (deterministic, edge-order stable) ----------------

__global__ void hist_kernel(const int* __restrict__ rows, int* __restrict__ counts, int nnz) {
    int e = blockIdx.x * blockDim.x + threadIdx.x;
    if (e < nnz) atomicAdd(&counts[rows[e]], 1);
}

__global__ __launch_bounds__(1024) void scan_kernel(const int* __restrict__ counts,
                                                    int* __restrict__ row_ptr,
                                                    int* __restrict__ cursor, int n) {
    __shared__ int partials[1024];
    int tid = threadIdx.x;
    int chunk = (n + 1023) >> 10;
    int start = tid * chunk;
    int end = start + chunk;
    if (end > n) end = n;
    if (start > n) start = n;
    int sum = 0;
    for (int i = start; i < end; ++i) sum += counts[i];
    partials[tid] = sum;
    __syncthreads();
    for (int off = 1; off < 1024; off <<= 1) {
        int v = (tid >= off) ? partials[tid - off] : 0;
        __syncthreads();
        partials[tid] += v;
        __syncthreads();
    }
    int run = (tid == 0) ? 0 : partials[tid - 1];
    for (int i = start; i < end; ++i) {
        int c = counts[i];
        row_ptr[i] = run;
        cursor[i]  = run;
        run += c;
    }
    if (tid == 1023) row_ptr[n] = partials[1023];
}

// scatter edge indices (arbitrary within-row order; fixed by sort below)
__global__ void scatter_kernel(const int* __restrict__ rows, int* __restrict__ cursor,
                               int* __restrict__ eidx, int nnz) {
    int e = blockIdx.x * blockDim.x + threadIdx.x;
    if (e < nnz) {
        int pos = atomicAdd(&cursor[rows[e]], 1);
        eidx[pos] = e;
    }
}

// per-row insertion sort in LDS (stable edge order = np.add.at order), fused with
// materialize of packed (col, val) records. Global-memory fallback for huge rows
// (deterministic for a fixed input; Poisson(32) makes deg>73 astronomically rare).
__global__ __launch_bounds__(128) void sortrows_kernel(const int* __restrict__ row_ptr,
                                                       int* __restrict__ eidx,
                                                       const int* __restrict__ cols,
                                                       const float* __restrict__ vals,
                                                       int2* __restrict__ cpack) {
    __shared__ int buf[128 * SLOT];
    int row = blockIdx.x * 128 + threadIdx.x;
    if (row >= NN) return;
    int beg = row_ptr[row], end = row_ptr[row + 1];
    int deg = end - beg;
    if (deg <= SLOT) {
        int* s = &buf[threadIdx.x * SLOT];
        for (int i = 0; i < deg; ++i) s[i] = eidx[beg + i];
        for (int i = 1; i < deg; ++i) {
            int key = s[i], j = i - 1;
            while (j >= 0 && s[j] > key) { s[j + 1] = s[j]; --j; }
            s[j + 1] = key;
        }
        for (int i = 0; i < deg; ++i) {
            int e = s[i];
            cpack[beg + i] = make_int2(cols[e], __float_as_int(vals[e]));
        }
    } else {
        for (int i = beg + 1; i < end; ++i) {
            int key = eidx[i], j = i - 1;
            while (j >= beg && eidx[j] > key) { eidx[j + 1] = eidx[j]; --j; }
            eidx[j + 1] = key;
        }
        for (int i = beg; i < end; ++i) {
            int e = eidx[i];
            cpack[beg + i] = make_int2(cols[e], __float_as_int(vals[e]));
        }
    }
}

// ---------------- row norms of noise: numpy AVX512 npyv pairwise order ----------------
// 16 lanes per row (lane l = AVX512 lane l):
//   rs_l = (q[l]+q[64+l]) + (q[16+l]+q[80+l])  +  ((q[32+l]+q[96+l]) + (q[48+l]+q[112+l]))
//   -- wait, exact: rs_l = (r0+r1)+(r2+r3) as below --
// then npyv_sum_f32 halving tree via shfl_xor 8,4,2,1.
__global__ __launch_bounds__(256) void norm_kernel(const float* __restrict__ noise,
                                                   float* __restrict__ nrm, int total) {
    int gid = blockIdx.x * blockDim.x + threadIdx.x;
    int rowi = gid >> 4;
    int l    = gid & 15;
    if (rowi >= total) return;
    const float* x = noise + (long long)rowi * DD;
    float q[8];
    #pragma unroll
    for (int k = 0; k < 8; ++k) {
        float t = x[16 * k + l];
        q[k] = __fmul_rn(t, t);
    }
    float r0 = __fadd_rn(q[0], q[4]);   // q[l]    + q[64+l]
    float r1 = __fadd_rn(q[1], q[5]);   // q[16+l] + q[80+l]
    float r2 = __fadd_rn(q[2], q[6]);   // q[32+l] + q[96+l]
    float r3 = __fadd_rn(q[3], q[7]);   // q[48+l] + q[112+l]
    float rs = __fadd_rn(__fadd_rn(r0, r1), __fadd_rn(r2, r3));
    float b = __fadd_rn(rs, __shfl_xor(rs, 8, 64));  // b_l = rs_l + rs_{l+8}
    float c = __fadd_rn(b,  __shfl_xor(b, 4, 64));   // c_l = b_l + b_{l+4}
    float d = __fadd_rn(c,  __shfl_xor(c, 2, 64));   // lane0: c0+c2, lane1: c1+c3
    float s = __fadd_rn(d,  __shfl_xor(d, 1, 64));   // (c0+c2)+(c1+c3)
    if (l == 0) nrm[rowi] = __fsqrt_rn(s);
}

// ---------------- fused SpMM + noise (+ final combine), strict f32 np order ----------------
// one wave per row; lane owns columns [2*lane, 2*lane+1]; edge loop unrolled x8 for MLP.

template <int LAYER>
__device__ __forceinline__ float2 gather_row(const float* __restrict__ xa,
                                             const float* __restrict__ xb,
                                             int c, int lane) {
    const float* p;
    if (LAYER == 1)
        p = (c < NUM_USERS_) ? (xa + (size_t)c * DD) : (xb + (size_t)(c - NUM_USERS_) * DD);
    else
        p = xa + (size_t)c * DD;
    return ((const float2*)p)[lane];
}

template <int LAYER>   // 1, 2, 3
__global__ __launch_bounds__(256) void layer_kernel(
    const int* __restrict__ row_ptr, const int2* __restrict__ cpack,
    const float* __restrict__ xa,    // L1: user_emb; L2/L3: gather source slab
    const float* __restrict__ xb,    // L1: item_emb; else unused
    const float* __restrict__ noise_k, const float* __restrict__ nrm_k,
    float* __restrict__ y_out,       // L1/L2: ego out slab; L3: final output
    const float* __restrict__ y1,    // L3: ego after layer 1
    const float* __restrict__ y2) {  // L3: ego after layer 2
    int wave = threadIdx.x >> 6;
    int lane = threadIdx.x & 63;
    int row  = blockIdx.x * 4 + wave;
    if (row >= NN) return;

    int beg = row_ptr[row];
    int end = row_ptr[row + 1];

    float a0 = 0.0f, a1 = 0.0f;
    int j = beg;
    // 8 independent gathers in flight; accumulate chain stays in exact edge order.
    for (; j + 8 <= end; j += 8) {
        int   c[8];
        float v[8];
        #pragma unroll
        for (int u = 0; u < 8; ++u) {
            int2 p = cpack[j + u];
            c[u] = p.x;
            v[u] = __int_as_float(p.y);
        }
        float2 xv[8];
        #pragma unroll
        for (int u = 0; u < 8; ++u) xv[u] = gather_row<LAYER>(xa, xb, c[u], lane);
        #pragma unroll
        for (int u = 0; u < 8; ++u) {
            a0 = __fadd_rn(a0, __fmul_rn(v[u], xv[u].x));
            a1 = __fadd_rn(a1, __fmul_rn(v[u], xv[u].y));
        }
    }
    for (; j < end; ++j) {
        int2 p = cpack[j];
        float2 xv = gather_row<LAYER>(xa, xb, p.x, lane);
        float v = __int_as_float(p.y);
        a0 = __fadd_rn(a0, __fmul_rn(v, xv.x));
        a1 = __fadd_rn(a1, __fmul_rn(v, xv.y));
    }

    float2 nv = ((const float2*)(noise_k + (long long)row * DD))[lane];
    float nrm = nrm_k[row];

    float s0 = (a0 > 0.0f) ? 1.0f : ((a0 < 0.0f) ? -1.0f : 0.0f);
    float s1 = (a1 > 0.0f) ? 1.0f : ((a1 < 0.0f) ? -1.0f : 0.0f);
    // np order: nk = n / nrm;  t = (sign * nk) * 0.2f;  ego = a + t
    float q0 = __fdiv_rn(nv.x, nrm);
    float q1 = __fdiv_rn(nv.y, nrm);
    float t0 = __fmul_rn(__fmul_rn(s0, q0), 0.2f);
    float t1 = __fmul_rn(__fmul_rn(s1, q1), 0.2f);
    float e0 = __fadd_rn(a0, t0);
    float e1 = __fadd_rn(a1, t1);

    if (LAYER < 3) {
        ((float2*)(y_out + (long long)row * DD))[lane] = make_float2(e0, e1);
    } else {
        // final = ((e1 + e2) + e3) / 3, identical __fadd_rn/__fdiv_rn chain as before
        float2 p1 = ((const float2*)(y1 + (long long)row * DD))[lane];
        float2 p2 = ((const float2*)(y2 + (long long)row * DD))[lane];
        float g0 = __fadd_rn(__fadd_rn(p1.x, p2.x), e0);
        float g1 = __fadd_rn(__fadd_rn(p1.y, p2.y), e1);
        ((float2*)(y_out + (long long)row * DD))[lane] =
            make_float2(__fdiv_rn(g0, 3.0f), __fdiv_rn(g1, 3.0f));
    }
}

extern "C" void kernel_launch(void* const* d_in, const int* in_sizes, int n_in,
                              void* d_out, int out_size, void* d_ws, size_t ws_size,
                              hipStream_t stream) {
    const float* user  = (const float*)d_in[0];
    const float* item  = (const float*)d_in[1];
    const float* vals  = (const float*)d_in[2];
    const float* noise = (const float*)d_in[3];
    const int*   rows  = (const int*)d_in[4];
    const int*   cols  = (const int*)d_in[5];
    float* out = (float*)d_out;

    char* ws = (char*)d_ws;
    size_t off = 0;
    auto alloc = [&](size_t bytes) -> char* {
        char* p = ws + off;
        off = (off + bytes + 255) & ~(size_t)255;
        return p;
    };

    int*   counts  = (int*)  alloc((size_t)NN * 4);
    int*   row_ptr = (int*)  alloc((size_t)(NN + 1) * 4);
    int*   cursor  = (int*)  alloc((size_t)NN * 4);
    int*   eidx    = (int*)  alloc((size_t)NNZ_ * 4);
    int2*  cpack   = (int2*) alloc((size_t)NNZ_ * 8);
    float* nrm     = (float*)alloc((size_t)NLAYERS_ * NN * 4);
    float* ego_a   = (float*)alloc((size_t)NN * DD * 4);
    float* ego_b   = (float*)alloc((size_t)NN * DD * 4);

    hipMemsetAsync(counts, 0, (size_t)NN * 4, stream);

    const int TB = 256;
    hist_kernel<<<(NNZ_ + TB - 1) / TB, TB, 0, stream>>>(rows, counts, NNZ_);
    scan_kernel<<<1, 1024, 0, stream>>>(counts, row_ptr, cursor, NN);
    scatter_kernel<<<(NNZ_ + TB - 1) / TB, TB, 0, stream>>>(rows, cursor, eidx, NNZ_);
    sortrows_kernel<<<(NN + 127) / 128, 128, 0, stream>>>(row_ptr, eidx, cols, vals, cpack);

    norm_kernel<<<((NLAYERS_ * NN * 16) + TB - 1) / TB, TB, 0, stream>>>(noise, nrm, NLAYERS_ * NN);

    const long long slab = (long long)NN * DD;
    int lgrid = (NN + 3) / 4;
    layer_kernel<1><<<lgrid, TB, 0, stream>>>(row_ptr, cpack, user, item,
                                              noise + 0 * slab, nrm + 0 * NN, ego_b, nullptr, nullptr);
    layer_kernel<2><<<lgrid, TB, 0, stream>>>(row_ptr, cpack, ego_b, nullptr,
                                              noise + 1 * slab, nrm + 1 * NN, ego_a, nullptr, nullptr);
    layer_kernel<3><<<lgrid, TB, 0, stream>>>(row_ptr, cpack, ego_a, nullptr,
                                              noise + 2 * slab, nrm + 2 * NN, out, ego_b, ego_a);
}

// Round 6
// 2269.387 us; speedup vs baseline: 1.2935x; 1.0036x over previous
//
#include <hip/hip_runtime.h>

#define NUM_USERS_ 50000
#define NUM_ITEMS_ 100000
#define NN 150000            // NUM_USERS + NUM_ITEMS
#define DD 128
#define NNZ_ 4800000
#define NLAYERS_ 3
#define SLOT 73              // per-row LDS sort budget
#define SUBR (NN / 8)        // 18750 rows per XCD subrange
#define EPSL 32768           // edges per slice for partitioned hist/scatter
#define NSLICE ((NNZ_ + EPSL - 1) / EPSL)   // 147

// ---------------- CSR build (deterministic, XCD-partitioned atomics) ----------------
// Grid = NSLICE*8. Block b: edge slice b>>3, row subrange (b&7)*SUBR .. +SUBR.
// With round-robin block->XCD dispatch, each XCD's atomic/store targets stay
// exclusive to its own L2 (no cross-XCD line bouncing). Correctness is
// independent of the mapping; only locality depends on it.

__global__ __launch_bounds__(256) void hist_kernel(const int* __restrict__ rows,
                                                   int* __restrict__ counts) {
    int slice = blockIdx.x >> 3;
    int sub   = blockIdx.x & 7;
    int lo = sub * SUBR, hi = lo + SUBR;
    int base = slice * EPSL;
    int stop = base + EPSL; if (stop > NNZ_) stop = NNZ_;
    for (int e = base + threadIdx.x; e < stop; e += 256) {
        int r = rows[e];
        if (r >= lo && r < hi) atomicAdd(&counts[r], 1);
    }
}

__global__ __launch_bounds__(1024) void scan_kernel(const int* __restrict__ counts,
                                                    int* __restrict__ row_ptr,
                                                    int* __restrict__ cursor, int n) {
    __shared__ int partials[1024];
    int tid = threadIdx.x;
    int chunk = (n + 1023) >> 10;
    int start = tid * chunk;
    int end = start + chunk;
    if (end > n) end = n;
    if (start > n) start = n;
    int sum = 0;
    for (int i = start; i < end; ++i) sum += counts[i];
    partials[tid] = sum;
    __syncthreads();
    for (int off = 1; off < 1024; off <<= 1) {
        int v = (tid >= off) ? partials[tid - off] : 0;
        __syncthreads();
        partials[tid] += v;
        __syncthreads();
    }
    int run = (tid == 0) ? 0 : partials[tid - 1];
    for (int i = start; i < end; ++i) {
        int c = counts[i];
        row_ptr[i] = run;
        cursor[i]  = run;
        run += c;
    }
    if (tid == 1023) row_ptr[n] = partials[1023];
}

__global__ __launch_bounds__(256) void scatter_kernel(const int* __restrict__ rows,
                                                      int* __restrict__ cursor,
                                                      int* __restrict__ eidx) {
    int slice = blockIdx.x >> 3;
    int sub   = blockIdx.x & 7;
    int lo = sub * SUBR, hi = lo + SUBR;
    int base = slice * EPSL;
    int stop = base + EPSL; if (stop > NNZ_) stop = NNZ_;
    for (int e = base + threadIdx.x; e < stop; e += 256) {
        int r = rows[e];
        if (r >= lo && r < hi) {
            int pos = atomicAdd(&cursor[r], 1);
            eidx[pos] = e;
        }
    }
}

// per-row insertion sort in LDS (stable edge order = np.add.at order), fused with
// materialize of packed (col, val) records. Global fallback for deg > SLOT.
__global__ __launch_bounds__(128) void sortrows_kernel(const int* __restrict__ row_ptr,
                                                       int* __restrict__ eidx,
                                                       const int* __restrict__ cols,
                                                       const float* __restrict__ vals,
                                                       int2* __restrict__ cpack) {
    __shared__ int buf[128 * SLOT];
    int row = blockIdx.x * 128 + threadIdx.x;
    if (row >= NN) return;
    int beg = row_ptr[row], end = row_ptr[row + 1];
    int deg = end - beg;
    if (deg <= SLOT) {
        int* s = &buf[threadIdx.x * SLOT];
        for (int i = 0; i < deg; ++i) s[i] = eidx[beg + i];
        for (int i = 1; i < deg; ++i) {
            int key = s[i], j = i - 1;
            while (j >= 0 && s[j] > key) { s[j + 1] = s[j]; --j; }
            s[j + 1] = key;
        }
        for (int i = 0; i < deg; ++i) {
            int e = s[i];
            cpack[beg + i] = make_int2(cols[e], __float_as_int(vals[e]));
        }
    } else {
        for (int i = beg + 1; i < end; ++i) {
            int key = eidx[i], j = i - 1;
            while (j >= beg && eidx[j] > key) { eidx[j + 1] = eidx[j]; --j; }
            eidx[j + 1] = key;
        }
        for (int i = beg; i < end; ++i) {
            int e = eidx[i];
            cpack[beg + i] = make_int2(cols[e], __float_as_int(vals[e]));
        }
    }
}

// ---------------- fused SpMM + in-wave npyv norm + noise (+ final combine) ----------------
// one wave per row; lane owns columns [2*lane, 2*lane+1]; edge loop unrolled x16.

template <int LAYER>
__device__ __forceinline__ float2 gather_row(const float* __restrict__ xa,
                                             const float* __restrict__ xb,
                                             int c, int lane) {
    const float* p;
    if (LAYER == 1)
        p = (c < NUM_USERS_) ? (xa + (size_t)c * DD) : (xb + (size_t)(c - NUM_USERS_) * DD);
    else
        p = xa + (size_t)c * DD;
    return ((const float2*)p)[lane];
}

template <int LAYER>   // 1, 2, 3
__global__ __launch_bounds__(256) void layer_kernel(
    const int* __restrict__ row_ptr, const int2* __restrict__ cpack,
    const float* __restrict__ xa,    // L1: user_emb; L2/L3: gather source slab
    const float* __restrict__ xb,    // L1: item_emb; else unused
    const float* __restrict__ noise_k,
    float* __restrict__ y_out,       // L1/L2: ego out slab; L3: final output
    const float* __restrict__ y1,    // L3: ego after layer 1
    const float* __restrict__ y2) {  // L3: ego after layer 2
    int wave = threadIdx.x >> 6;
    int lane = threadIdx.x & 63;
    int row  = blockIdx.x * 4 + wave;
    if (row >= NN) return;

    int beg = row_ptr[row];
    int end = row_ptr[row + 1];

    float a0 = 0.0f, a1 = 0.0f;
    // 16 independent gathers in flight; masked tail (v=0 -> a+(+/-0)==a bitwise,
    // accumulator can never be -0). Accumulate chain stays in exact edge order.
    for (int j = beg; j < end; j += 16) {
        int   c[16];
        float v[16];
        #pragma unroll
        for (int u = 0; u < 16; ++u) {
            int jj = j + u;
            int k  = (jj < end) ? jj : (end - 1);
            int2 p = cpack[k];
            c[u] = p.x;
            v[u] = (jj < end) ? __int_as_float(p.y) : 0.0f;
        }
        float2 xv[16];
        #pragma unroll
        for (int u = 0; u < 16; ++u) xv[u] = gather_row<LAYER>(xa, xb, c[u], lane);
        #pragma unroll
        for (int u = 0; u < 16; ++u) {
            a0 = __fadd_rn(a0, __fmul_rn(v[u], xv[u].x));
            a1 = __fadd_rn(a1, __fmul_rn(v[u], xv[u].y));
        }
    }

    // noise row + in-wave exact npyv pairwise norm:
    // rs = (r0+r1)+(r2+r3) via xor32, then xor8 (r0+r1 / r2+r3), then xor16;
    // npyv_sum halving tree via xor4, xor2, xor1; final .x+.y.
    // IEEE RN addition is commutative -> every lane's result is bit-identical.
    float2 nv = ((const float2*)(noise_k + (long long)row * DD))[lane];
    float sx = __fmul_rn(nv.x, nv.x);
    float sy = __fmul_rn(nv.y, nv.y);
    float tx = __fadd_rn(sx, __shfl_xor(sx, 32, 64));
    float ty = __fadd_rn(sy, __shfl_xor(sy, 32, 64));
    tx = __fadd_rn(tx, __shfl_xor(tx, 8, 64));
    ty = __fadd_rn(ty, __shfl_xor(ty, 8, 64));
    tx = __fadd_rn(tx, __shfl_xor(tx, 16, 64));
    ty = __fadd_rn(ty, __shfl_xor(ty, 16, 64));
    tx = __fadd_rn(tx, __shfl_xor(tx, 4, 64));
    ty = __fadd_rn(ty, __shfl_xor(ty, 4, 64));
    tx = __fadd_rn(tx, __shfl_xor(tx, 2, 64));
    ty = __fadd_rn(ty, __shfl_xor(ty, 2, 64));
    tx = __fadd_rn(tx, __shfl_xor(tx, 1, 64));
    ty = __fadd_rn(ty, __shfl_xor(ty, 1, 64));
    float nrm = __fsqrt_rn(__fadd_rn(tx, ty));

    float s0 = (a0 > 0.0f) ? 1.0f : ((a0 < 0.0f) ? -1.0f : 0.0f);
    float s1 = (a1 > 0.0f) ? 1.0f : ((a1 < 0.0f) ? -1.0f : 0.0f);
    // np order: nk = n / nrm;  t = (sign * nk) * 0.2f;  ego = a + t
    float q0 = __fdiv_rn(nv.x, nrm);
    float q1 = __fdiv_rn(nv.y, nrm);
    float t0 = __fmul_rn(__fmul_rn(s0, q0), 0.2f);
    float t1 = __fmul_rn(__fmul_rn(s1, q1), 0.2f);
    float e0 = __fadd_rn(a0, t0);
    float e1 = __fadd_rn(a1, t1);

    if (LAYER < 3) {
        ((float2*)(y_out + (long long)row * DD))[lane] = make_float2(e0, e1);
    } else {
        // final = ((e1 + e2) + e3) / 3, identical __fadd_rn/__fdiv_rn chain
        float2 p1 = ((const float2*)(y1 + (long long)row * DD))[lane];
        float2 p2 = ((const float2*)(y2 + (long long)row * DD))[lane];
        float g0 = __fadd_rn(__fadd_rn(p1.x, p2.x), e0);
        float g1 = __fadd_rn(__fadd_rn(p1.y, p2.y), e1);
        ((float2*)(y_out + (long long)row * DD))[lane] =
            make_float2(__fdiv_rn(g0, 3.0f), __fdiv_rn(g1, 3.0f));
    }
}

extern "C" void kernel_launch(void* const* d_in, const int* in_sizes, int n_in,
                              void* d_out, int out_size, void* d_ws, size_t ws_size,
                              hipStream_t stream) {
    const float* user  = (const float*)d_in[0];
    const float* item  = (const float*)d_in[1];
    const float* vals  = (const float*)d_in[2];
    const float* noise = (const float*)d_in[3];
    const int*   rows  = (const int*)d_in[4];
    const int*   cols  = (const int*)d_in[5];
    float* out = (float*)d_out;

    char* ws = (char*)d_ws;
    size_t off = 0;
    auto alloc = [&](size_t bytes) -> char* {
        char* p = ws + off;
        off = (off + bytes + 255) & ~(size_t)255;
        return p;
    };

    int*   counts  = (int*)  alloc((size_t)NN * 4);
    int*   row_ptr = (int*)  alloc((size_t)(NN + 1) * 4);
    int*   cursor  = (int*)  alloc((size_t)NN * 4);
    int*   eidx    = (int*)  alloc((size_t)NNZ_ * 4);
    int2*  cpack   = (int2*) alloc((size_t)NNZ_ * 8);
    float* ego_a   = (float*)alloc((size_t)NN * DD * 4);
    float* ego_b   = (float*)alloc((size_t)NN * DD * 4);

    hipMemsetAsync(counts, 0, (size_t)NN * 4, stream);

    hist_kernel<<<NSLICE * 8, 256, 0, stream>>>(rows, counts);
    scan_kernel<<<1, 1024, 0, stream>>>(counts, row_ptr, cursor, NN);
    scatter_kernel<<<NSLICE * 8, 256, 0, stream>>>(rows, cursor, eidx);
    sortrows_kernel<<<(NN + 127) / 128, 128, 0, stream>>>(row_ptr, eidx, cols, vals, cpack);

    const long long slab = (long long)NN * DD;
    int lgrid = (NN + 3) / 4;
    layer_kernel<1><<<lgrid, 256, 0, stream>>>(row_ptr, cpack, user, item,
                                               noise + 0 * slab, ego_b, nullptr, nullptr);
    layer_kernel<2><<<lgrid, 256, 0, stream>>>(row_ptr, cpack, ego_b, nullptr,
                                               noise + 1 * slab, ego_a, nullptr, nullptr);
    layer_kernel<3><<<lgrid, 256, 0, stream>>>(row_ptr, cpack, ego_a, nullptr,
                                               noise + 2 * slab, out, ego_b, ego_a);
}